// Round 2
// baseline (3784.130 us; speedup 1.0000x reference)
//
#include <hip/hip_runtime.h>

typedef unsigned short u16;
using bf8   = __attribute__((ext_vector_type(8))) short;  // 8 bf16 (4 VGPRs)
using bf4   = __attribute__((ext_vector_type(4))) short;  // 4 bf16
using f32x4 = __attribute__((ext_vector_type(4))) float;

#define B_ 256
#define T_ 512
#define D_ 64
#define H_ 256

#define MFMA(a, b, c) __builtin_amdgcn_mfma_f32_16x16x32_bf16(a, b, c, 0, 0, 0)

static __device__ inline u16 f2b(float f) {
    unsigned int u = __float_as_uint(f);
    unsigned int r = (u + 0x7fffu + ((u >> 16) & 1u)) >> 16;
    return (u16)r;
}
static __device__ inline float fast_tanh(float x) {
    float e = __expf(2.f * x);
    return 1.f - 2.f / (e + 1.f);
}
static __device__ inline float fast_sigmoid(float x) {
    return 1.f / (1.f + __expf(-x));
}

// ---------------------------------------------------------------------------
// k_conv: f32 -> bf16 weight conversion pre-pass (runs every launch; ws is
// re-poisoned by the harness before each timed call).
// ---------------------------------------------------------------------------
__global__ __launch_bounds__(256) void k_conv(
    const float* __restrict__ W1w, const float* __restrict__ U1w,
    const float* __restrict__ W2w, const float* __restrict__ U2w,
    const float* __restrict__ o1w, const float* __restrict__ o2w,
    const float* __restrict__ gw,
    u16* W1bf, u16* U1bf, u16* W2bf, u16* U2bf,
    u16* o1bf, u16* o2bf, u16* gbf)
{
    const int a = blockIdx.y;
    const float* src; u16* dst; int n;
    switch (a) {
        case 0: src = W1w; dst = W1bf; n = 16384;  break;
        case 1: src = U1w; dst = U1bf; n = 65536;  break;
        case 2: src = W2w; dst = W2bf; n = 65536;  break;
        case 3: src = U2w; dst = U2bf; n = 65536;  break;
        case 4: src = o1w; dst = o1bf; n = 16384;  break;
        case 5: src = o2w; dst = o2bf; n = 16384;  break;
        default: src = gw; dst = gbf;  n = 131072; break;
    }
    const int i = (blockIdx.x * 256 + threadIdx.x) * 4;
    if (i < n) {
        f32x4 v = *(const f32x4*)(src + i);
        bf4 o;
        o[0] = (short)f2b(v[0]); o[1] = (short)f2b(v[1]);
        o[2] = (short)f2b(v[2]); o[3] = (short)f2b(v[3]);
        *(bf4*)(dst + i) = o;
    }
}

// ---------------------------------------------------------------------------
// K_A: h1 recurrence. 16 blocks x 256 threads (4 waves, 1 wave/SIMD).
// Block g owns batches [16g, 16g+16). All of U1,W1 live in registers as
// MFMA B-fragments. h1 state round-trips through LDS each step.
// Writes H1 as [tt][b][h] bf16.
// ---------------------------------------------------------------------------
__global__ __launch_bounds__(256, 1) void k_h1(
    const float* __restrict__ x, const u16* __restrict__ W1,
    const u16* __restrict__ U1, const float* __restrict__ W1b,
    const float* __restrict__ U1b, u16* __restrict__ H1,
    u16* __restrict__ h1state, int t0, int Tc)
{
    const int g = blockIdx.x;
    const int tid = threadIdx.x;
    const int w = tid >> 6, lane = tid & 63;
    const int col = lane & 15, quad = lane >> 4;

    __shared__ __align__(16) u16 h1buf[16][H_ + 8];

    // weight fragments: wave w owns n-tiles 4w..4w+3 (output cols 64w..64w+64)
    bf8 u1f[4][8], w1f[4][2];
    float bias[4];
#pragma unroll
    for (int i = 0; i < 4; ++i) {
        const int n = (w * 4 + i) * 16 + col;
#pragma unroll
        for (int kt = 0; kt < 8; ++kt)
            u1f[i][kt] = *(const bf8*)(U1 + (size_t)n * H_ + kt * 32 + quad * 8);
#pragma unroll
        for (int kt = 0; kt < 2; ++kt)
            w1f[i][kt] = *(const bf8*)(W1 + (size_t)n * D_ + kt * 32 + quad * 8);
        bias[i] = W1b[n] + U1b[n];
    }

    // init h1 state in LDS
    if (t0 == 0) {
        for (int idx = tid; idx < 16 * (H_ + 8); idx += 256)
            ((u16*)h1buf)[idx] = 0;
    } else {
        const int m = tid >> 4, hb = (tid & 15) * 16;
#pragma unroll
        for (int j = 0; j < 16; ++j)
            h1buf[m][hb + j] = h1state[(size_t)(g * 16 + m) * H_ + hb + j];
    }
    __syncthreads();

    for (int tt = 0; tt < Tc; ++tt) {
        const int t = t0 + tt;
        // A-fragments: h1_prev from LDS, x_t from global (f32 -> bf16)
        bf8 haf[8], xaf[2];
#pragma unroll
        for (int kt = 0; kt < 8; ++kt)
            haf[kt] = *(const bf8*)&h1buf[col][kt * 32 + quad * 8];
        {
            const float* xp = x + ((size_t)(g * 16 + col) * T_ + t) * D_;
#pragma unroll
            for (int kt = 0; kt < 2; ++kt) {
                f32x4 a = *(const f32x4*)(xp + kt * 32 + quad * 8);
                f32x4 b = *(const f32x4*)(xp + kt * 32 + quad * 8 + 4);
                bf8 v;
                v[0] = (short)f2b(a[0]); v[1] = (short)f2b(a[1]);
                v[2] = (short)f2b(a[2]); v[3] = (short)f2b(a[3]);
                v[4] = (short)f2b(b[0]); v[5] = (short)f2b(b[1]);
                v[6] = (short)f2b(b[2]); v[7] = (short)f2b(b[3]);
                xaf[kt] = v;
            }
        }
        __syncthreads();  // all A-frag reads done before h1buf overwrite

        f32x4 acc[4];
#pragma unroll
        for (int i = 0; i < 4; ++i) {
            acc[i][0] = bias[i]; acc[i][1] = bias[i];
            acc[i][2] = bias[i]; acc[i][3] = bias[i];
#pragma unroll
            for (int kt = 0; kt < 8; ++kt)
                acc[i] = MFMA(haf[kt], u1f[i][kt], acc[i]);
#pragma unroll
            for (int kt = 0; kt < 2; ++kt)
                acc[i] = MFMA(xaf[kt], w1f[i][kt], acc[i]);
        }
        // tanh + write new h1 to LDS (C-layout scatter: row=batch, col=n)
#pragma unroll
        for (int i = 0; i < 4; ++i) {
            const int n = (w * 4 + i) * 16 + col;
#pragma unroll
            for (int r = 0; r < 4; ++r)
                h1buf[quad * 4 + r][n] = f2b(fast_tanh(acc[i][r]));
        }
        __syncthreads();
        // coalesced copy LDS -> global H1 [tt][b][h]
        {
            const int m = tid >> 4, hb = (tid & 15) * 16;
            bf8 v0 = *(const bf8*)&h1buf[m][hb];
            bf8 v1 = *(const bf8*)&h1buf[m][hb + 8];
            u16* dst = H1 + ((size_t)tt * 256 + g * 16 + m) * H_ + hb;
            *(bf8*)dst = v0;
            *(bf8*)(dst + 8) = v1;
        }
    }
    __syncthreads();
    {   // save state for next chunk
        const int m = tid >> 4, hb = (tid & 15) * 16;
#pragma unroll
        for (int j = 0; j < 16; ++j)
            h1state[(size_t)(g * 16 + m) * H_ + hb + j] = h1buf[m][hb + j];
    }
}

// ---------------------------------------------------------------------------
// K_G: parallel GEMM over the chunk. out[(tt,b), n] for n in [0,576):
//   n in [0,256)   -> W2 @ h1 + (W2_b + U2_b)   -> W2c   (h2 preact partial)
//   n in [256,512) -> g1 @ h1 + g_b             -> G1c   (u preact partial)
//   n in [512,576) -> o1 @ h1 + o1_b + o2_b     -> O1c   (out partial)
// Outputs stored f32 in the exact per-lane fragment order K_C consumes.
// ---------------------------------------------------------------------------
__global__ __launch_bounds__(256, 1) void k_gemm(
    const u16* __restrict__ H1,
    const u16* __restrict__ W2, const u16* __restrict__ gw,
    const u16* __restrict__ o1w,
    const float* __restrict__ W2b, const float* __restrict__ U2b,
    const float* __restrict__ gb, const float* __restrict__ o1b,
    const float* __restrict__ o2b,
    float* __restrict__ W2c, float* __restrict__ G1c, float* __restrict__ O1c,
    int Tc)
{
    const int mt = blockIdx.x, ny = blockIdx.y;
    const int tid = threadIdx.x;
    const int w = tid >> 6, lane = tid & 63;
    const int col = lane & 15, quad = lane >> 4;
    const int mrow = mt * 64 + w * 16;  // global M-row base (= tt*256 + b)

    f32x4 acc[4];
#pragma unroll
    for (int i = 0; i < 4; ++i) { acc[i][0]=0.f; acc[i][1]=0.f; acc[i][2]=0.f; acc[i][3]=0.f; }

#pragma unroll
    for (int kt = 0; kt < 8; ++kt) {
        const int k = kt * 32 + quad * 8;
        bf8 af = *(const bf8*)(H1 + (size_t)(mrow + col) * H_ + k);
#pragma unroll
        for (int i = 0; i < 4; ++i) {
            const int n = ny * 64 + i * 16 + col;
            const u16* bp;
            if (n < 256)      bp = W2  + (size_t)n * H_ + k;
            else if (n < 512) bp = gw  + (size_t)(n - 256) * (2 * H_) + k;
            else              bp = o1w + (size_t)(n - 512) * H_ + k;
            bf8 bfv = *(const bf8*)bp;
            acc[i] = MFMA(af, bfv, acc[i]);
        }
    }

    const int tt = mrow >> 8;
    const int g  = (mrow & 255) >> 4;
#pragma unroll
    for (int i = 0; i < 4; ++i) {
        const int n = ny * 64 + i * 16 + col;
        float bias;
        if (n < 256)      bias = W2b[n] + U2b[n];
        else if (n < 512) bias = gb[n - 256];
        else              bias = o1b[n - 512] + o2b[n - 512];
        f32x4 v;
#pragma unroll
        for (int r = 0; r < 4; ++r) v[r] = acc[i][r] + bias;
        const int nt = ny * 4 + i;
        if (nt < 16) {
            size_t idx = ((((size_t)g * Tc + tt) * 16 + nt) * 64 + lane) * 4;
            *(f32x4*)(W2c + idx) = v;
        } else if (nt < 32) {
            size_t idx = ((((size_t)g * Tc + tt) * 16 + (nt - 16)) * 64 + lane) * 4;
            *(f32x4*)(G1c + idx) = v;
        } else {
            size_t idx = ((((size_t)g * Tc + tt) * 4 + (nt - 32)) * 64 + lane) * 4;
            *(f32x4*)(O1c + idx) = v;
        }
    }
}

// ---------------------------------------------------------------------------
// K_C: h2/u/out recurrence. 16 blocks x 256 threads (4 waves).
// In-loop weights U2, g2 (= g_w[:,256:]), o2 as register B-fragments.
// ---------------------------------------------------------------------------
__global__ __launch_bounds__(256, 1) void k_h2(
    const u16* __restrict__ U2, const u16* __restrict__ gw,
    const u16* __restrict__ o2w,
    const float* __restrict__ W2c, const float* __restrict__ G1c,
    const float* __restrict__ O1c,
    float* __restrict__ out, float* __restrict__ h2state,
    float* __restrict__ ustate, int t0, int Tc)
{
    const int g = blockIdx.x;
    const int tid = threadIdx.x;
    const int w = tid >> 6, lane = tid & 63;
    const int col = lane & 15, quad = lane >> 4;

    __shared__ __align__(16) u16 h2buf[16][H_ + 8];

    bf8 u2f[4][8], g2f[4][8], o2f[8];
#pragma unroll
    for (int i = 0; i < 4; ++i) {
        const int n = (w * 4 + i) * 16 + col;
#pragma unroll
        for (int kt = 0; kt < 8; ++kt) {
            u2f[i][kt] = *(const bf8*)(U2 + (size_t)n * H_ + kt * 32 + quad * 8);
            g2f[i][kt] = *(const bf8*)(gw + (size_t)n * (2 * H_) + H_ + kt * 32 + quad * 8);
        }
    }
#pragma unroll
    for (int kt = 0; kt < 8; ++kt)
        o2f[kt] = *(const bf8*)(o2w + (size_t)(w * 16 + col) * H_ + kt * 32 + quad * 8);

    f32x4 h2p[4], up[4];
    if (t0 == 0) {
#pragma unroll
        for (int i = 0; i < 4; ++i) {
            h2p[i][0]=0.f; h2p[i][1]=0.f; h2p[i][2]=0.f; h2p[i][3]=0.f;
            up[i][0]=1.f;  up[i][1]=1.f;  up[i][2]=1.f;  up[i][3]=1.f;
        }
    } else {
#pragma unroll
        for (int i = 0; i < 4; ++i) {
            size_t idx = (((size_t)g * 16 + (w * 4 + i)) * 64 + lane) * 4;
            h2p[i] = *(const f32x4*)(h2state + idx);
            up[i]  = *(const f32x4*)(ustate + idx);
        }
    }

    // seed LDS with h2_prev, load A-fragments
#pragma unroll
    for (int i = 0; i < 4; ++i) {
        const int n = (w * 4 + i) * 16 + col;
#pragma unroll
        for (int r = 0; r < 4; ++r) h2buf[quad * 4 + r][n] = f2b(h2p[i][r]);
    }
    __syncthreads();
    bf8 h2af[8];
#pragma unroll
    for (int kt = 0; kt < 8; ++kt)
        h2af[kt] = *(const bf8*)&h2buf[col][kt * 32 + quad * 8];
    __syncthreads();

    for (int tt = 0; tt < Tc; ++tt) {
        const int t = t0 + tt;
        // h2n preact = (W2@h1 + biases) + U2 @ h2_prev
        f32x4 acc1[4];
#pragma unroll
        for (int i = 0; i < 4; ++i) {
            size_t idx = ((((size_t)g * Tc + tt) * 16 + (w * 4 + i)) * 64 + lane) * 4;
            acc1[i] = *(const f32x4*)(W2c + idx);
        }
#pragma unroll
        for (int i = 0; i < 4; ++i)
#pragma unroll
            for (int kt = 0; kt < 8; ++kt)
                acc1[i] = MFMA(h2af[kt], u2f[i][kt], acc1[i]);
        // gated blend (all C-layout registers)
#pragma unroll
        for (int i = 0; i < 4; ++i)
#pragma unroll
            for (int r = 0; r < 4; ++r) {
                float h2n = fast_tanh(acc1[i][r]);
                h2p[i][r] = up[i][r] * h2n + (1.f - up[i][r]) * h2p[i][r];
            }
        // h2 -> LDS, reload A-frags (used by o2, g2 now and U2 next step)
#pragma unroll
        for (int i = 0; i < 4; ++i) {
            const int n = (w * 4 + i) * 16 + col;
#pragma unroll
            for (int r = 0; r < 4; ++r) h2buf[quad * 4 + r][n] = f2b(h2p[i][r]);
        }
        __syncthreads();
#pragma unroll
        for (int kt = 0; kt < 8; ++kt)
            h2af[kt] = *(const bf8*)&h2buf[col][kt * 32 + quad * 8];
        __syncthreads();
        // out_t = (o1@h1 + o1_b + o2_b) + o2 @ h2   (wave w owns d-tile w)
        {
            size_t idx = ((((size_t)g * Tc + tt) * 4 + w) * 64 + lane) * 4;
            f32x4 acco = *(const f32x4*)(O1c + idx);
#pragma unroll
            for (int kt = 0; kt < 8; ++kt)
                acco = MFMA(h2af[kt], o2f[kt], acco);
#pragma unroll
            for (int r = 0; r < 4; ++r)
                out[((size_t)(g * 16 + quad * 4 + r) * T_ + t) * D_ + w * 16 + col] =
                    acco[r];
        }
        // u_t = sigmoid(g1@h1 + g_b + g2 @ h2)
#pragma unroll
        for (int i = 0; i < 4; ++i) {
            size_t idx = ((((size_t)g * Tc + tt) * 16 + (w * 4 + i)) * 64 + lane) * 4;
            f32x4 a = *(const f32x4*)(G1c + idx);
#pragma unroll
            for (int kt = 0; kt < 8; ++kt)
                a = MFMA(h2af[kt], g2f[i][kt], a);
#pragma unroll
            for (int r = 0; r < 4; ++r) up[i][r] = fast_sigmoid(a[r]);
        }
    }
    // save states (register C-layout order)
#pragma unroll
    for (int i = 0; i < 4; ++i) {
        size_t idx = (((size_t)g * 16 + (w * 4 + i)) * 64 + lane) * 4;
        *(f32x4*)(h2state + idx) = h2p[i];
        *(f32x4*)(ustate + idx)  = up[i];
    }
}

// ---------------------------------------------------------------------------
extern "C" void kernel_launch(void* const* d_in, const int* in_sizes, int n_in,
                              void* d_out, int out_size, void* d_ws, size_t ws_size,
                              hipStream_t stream)
{
    const float* x   = (const float*)d_in[0];
    const float* W1w = (const float*)d_in[1];
    const float* W1b = (const float*)d_in[2];
    const float* U1w = (const float*)d_in[3];
    const float* U1b = (const float*)d_in[4];
    const float* W2w = (const float*)d_in[5];
    const float* W2b = (const float*)d_in[6];
    const float* U2w = (const float*)d_in[7];
    const float* U2b = (const float*)d_in[8];
    const float* o1w = (const float*)d_in[9];
    const float* o1b = (const float*)d_in[10];
    const float* o2w = (const float*)d_in[11];
    const float* o2b = (const float*)d_in[12];
    const float* gw  = (const float*)d_in[13];
    const float* gb  = (const float*)d_in[14];
    float* out = (float*)d_out;
    (void)in_sizes; (void)n_in; (void)out_size;

    // pick largest T-chunk whose workspace fits
    const size_t fixed = 753664 + 131072 + 262144 + 262144;
    int Tc = 32;
    for (int tc = 512; tc >= 32; tc >>= 1) {
        size_t need = (size_t)tc * 720896 + fixed;
        if (need <= ws_size) { Tc = tc; break; }
    }

    char* p = (char*)d_ws;
    u16* W1bf = (u16*)p; p += 16384 * 2;
    u16* U1bf = (u16*)p; p += 65536 * 2;
    u16* W2bf = (u16*)p; p += 65536 * 2;
    u16* U2bf = (u16*)p; p += 65536 * 2;
    u16* o1bf = (u16*)p; p += 16384 * 2;
    u16* o2bf = (u16*)p; p += 16384 * 2;
    u16* gbf  = (u16*)p; p += 131072 * 2;
    u16* H1   = (u16*)p; p += (size_t)Tc * 131072;
    float* W2c = (float*)p; p += (size_t)Tc * 262144;
    float* G1c = (float*)p; p += (size_t)Tc * 262144;
    float* O1c = (float*)p; p += (size_t)Tc * 65536;
    u16* h1s  = (u16*)p;  p += 131072;
    float* h2s = (float*)p; p += 262144;
    float* us  = (float*)p;

    k_conv<<<dim3(128, 7), 256, 0, stream>>>(W1w, U1w, W2w, U2w, o1w, o2w, gw,
                                             W1bf, U1bf, W2bf, U2bf, o1bf, o2bf, gbf);

    for (int t0 = 0; t0 < T_; t0 += Tc) {
        k_h1<<<16, 256, 0, stream>>>(x, W1bf, U1bf, W1b, U1b, H1, h1s, t0, Tc);
        k_gemm<<<dim3(Tc * 4, 9), 256, 0, stream>>>(H1, W2bf, gbf, o1bf, W2b, U2b,
                                                    gb, o1b, o2b, W2c, G1c, O1c, Tc);
        k_h2<<<16, 256, 0, stream>>>(U2bf, gbf, o2bf, W2c, G1c, O1c, out, h2s, us, t0, Tc);
    }
}

// Round 3
// 1824.621 us; speedup vs baseline: 2.0739x; 2.0739x over previous
//
#include <hip/hip_runtime.h>

typedef unsigned short u16;
using bf8   = __attribute__((ext_vector_type(8))) short;  // 8 bf16 (4 VGPRs)
using bf4   = __attribute__((ext_vector_type(4))) short;  // 4 bf16
using f32x4 = __attribute__((ext_vector_type(4))) float;

#define B_ 256
#define T_ 512
#define D_ 64
#define H_ 256
#define Tc_ 64
#define NC_ (T_ / Tc_)

#define MFMA(a, b, c) __builtin_amdgcn_mfma_f32_16x16x32_bf16(a, b, c, 0, 0, 0)

static __device__ inline u16 f2b(float f) {
    unsigned int u = __float_as_uint(f);
    unsigned int r = (u + 0x7fffu + ((u >> 16) & 1u)) >> 16;
    return (u16)r;
}
static __device__ inline float fast_tanh(float x) {
    float e = __expf(2.f * x);
    return 1.f - 2.f / (e + 1.f);
}
static __device__ inline float fast_sigmoid(float x) {
    return 1.f / (1.f + __expf(-x));
}

// ---------------------------------------------------------------------------
// k_conv: f32 -> bf16 weight conversion pre-pass.
// ---------------------------------------------------------------------------
__global__ __launch_bounds__(256) void k_conv(
    const float* __restrict__ W1w, const float* __restrict__ U1w,
    const float* __restrict__ W2w, const float* __restrict__ U2w,
    const float* __restrict__ o1w, const float* __restrict__ o2w,
    const float* __restrict__ gw,
    u16* W1bf, u16* U1bf, u16* W2bf, u16* U2bf,
    u16* o1bf, u16* o2bf, u16* gbf)
{
    const int a = blockIdx.y;
    const float* src; u16* dst; int n;
    switch (a) {
        case 0: src = W1w; dst = W1bf; n = 16384;  break;
        case 1: src = U1w; dst = U1bf; n = 65536;  break;
        case 2: src = W2w; dst = W2bf; n = 65536;  break;
        case 3: src = U2w; dst = U2bf; n = 65536;  break;
        case 4: src = o1w; dst = o1bf; n = 16384;  break;
        case 5: src = o2w; dst = o2bf; n = 16384;  break;
        default: src = gw; dst = gbf;  n = 131072; break;
    }
    const int i = (blockIdx.x * 256 + threadIdx.x) * 4;
    if (i < n) {
        f32x4 v = *(const f32x4*)(src + i);
        bf4 o;
        o[0] = (short)f2b(v[0]); o[1] = (short)f2b(v[1]);
        o[2] = (short)f2b(v[2]); o[3] = (short)f2b(v[3]);
        *(bf4*)(dst + i) = o;
    }
}

// ---------------------------------------------------------------------------
// h1 role: blocks 0-15 of k_pipe. Chunk c. x prefetched one step ahead.
// ---------------------------------------------------------------------------
__device__ void h1_role(
    const float* __restrict__ x, const u16* __restrict__ W1,
    const u16* __restrict__ U1, const float* __restrict__ W1b,
    const float* __restrict__ U1b, u16* __restrict__ H1,
    u16* __restrict__ h1state, int c, u16 (*buf)[H_ + 8])
{
    const int g = blockIdx.x;
    const int tid = threadIdx.x;
    const int w = tid >> 6, lane = tid & 63;
    const int col = lane & 15, quad = lane >> 4;
    const int t0 = c * Tc_;

    bf8 u1f[4][8], w1f[4][2];
    float bias[4];
#pragma unroll
    for (int i = 0; i < 4; ++i) {
        const int n = (w * 4 + i) * 16 + col;
#pragma unroll
        for (int kt = 0; kt < 8; ++kt)
            u1f[i][kt] = *(const bf8*)(U1 + (size_t)n * H_ + kt * 32 + quad * 8);
#pragma unroll
        for (int kt = 0; kt < 2; ++kt)
            w1f[i][kt] = *(const bf8*)(W1 + (size_t)n * D_ + kt * 32 + quad * 8);
        bias[i] = W1b[n] + U1b[n];
    }

    if (c == 0) {
        for (int idx = tid; idx < 16 * (H_ + 8); idx += 256)
            ((u16*)buf)[idx] = 0;
    } else {
        const int m = tid >> 4, hb = (tid & 15) * 16;
#pragma unroll
        for (int j = 0; j < 16; ++j)
            buf[m][hb + j] = h1state[(size_t)(g * 16 + m) * H_ + hb + j];
    }
    __syncthreads();

    const float* xrow = x + (size_t)(g * 16 + col) * T_ * D_ + quad * 8;
    f32x4 xa[4];
    {
        const float* xp = xrow + (size_t)t0 * D_;
        xa[0] = *(const f32x4*)xp;       xa[1] = *(const f32x4*)(xp + 4);
        xa[2] = *(const f32x4*)(xp + 32); xa[3] = *(const f32x4*)(xp + 36);
    }

    for (int tt = 0; tt < Tc_; ++tt) {
        const int tn = t0 + (tt + 1 < Tc_ ? tt + 1 : tt);
        f32x4 xan[4];
        {
            const float* xp = xrow + (size_t)tn * D_;
            xan[0] = *(const f32x4*)xp;       xan[1] = *(const f32x4*)(xp + 4);
            xan[2] = *(const f32x4*)(xp + 32); xan[3] = *(const f32x4*)(xp + 36);
        }
        bf8 haf[8];
#pragma unroll
        for (int kt = 0; kt < 8; ++kt)
            haf[kt] = *(const bf8*)&buf[col][kt * 32 + quad * 8];
        __syncthreads();  // reads done before overwrite

        bf8 xaf[2];
#pragma unroll
        for (int kt = 0; kt < 2; ++kt) {
            bf8 v;
#pragma unroll
            for (int j = 0; j < 4; ++j) {
                v[j]     = (short)f2b(xa[kt * 2][j]);
                v[j + 4] = (short)f2b(xa[kt * 2 + 1][j]);
            }
            xaf[kt] = v;
        }

        f32x4 acc[4];
#pragma unroll
        for (int i = 0; i < 4; ++i) {
            acc[i][0] = bias[i]; acc[i][1] = bias[i];
            acc[i][2] = bias[i]; acc[i][3] = bias[i];
        }
#pragma unroll
        for (int kt = 0; kt < 8; ++kt)
#pragma unroll
            for (int i = 0; i < 4; ++i)
                acc[i] = MFMA(haf[kt], u1f[i][kt], acc[i]);
#pragma unroll
        for (int kt = 0; kt < 2; ++kt)
#pragma unroll
            for (int i = 0; i < 4; ++i)
                acc[i] = MFMA(xaf[kt], w1f[i][kt], acc[i]);

#pragma unroll
        for (int i = 0; i < 4; ++i) {
            const int n = (w * 4 + i) * 16 + col;
#pragma unroll
            for (int r = 0; r < 4; ++r)
                buf[quad * 4 + r][n] = f2b(fast_tanh(acc[i][r]));
        }
        __syncthreads();
        {
            const int m = tid >> 4, hb = (tid & 15) * 16;
            bf8 v0 = *(const bf8*)&buf[m][hb];
            bf8 v1 = *(const bf8*)&buf[m][hb + 8];
            u16* dst = H1 + ((size_t)tt * 256 + g * 16 + m) * H_ + hb;
            *(bf8*)dst = v0;
            *(bf8*)(dst + 8) = v1;
        }
        xa[0] = xan[0]; xa[1] = xan[1]; xa[2] = xan[2]; xa[3] = xan[3];
    }
    __syncthreads();
    {
        const int m = tid >> 4, hb = (tid & 15) * 16;
#pragma unroll
        for (int j = 0; j < 16; ++j)
            h1state[(size_t)(g * 16 + m) * H_ + hb + j] = buf[m][hb + j];
    }
}

// ---------------------------------------------------------------------------
// h2 role: blocks 16-31 of k_pipe. Chunk cm1. Globals prefetched one step
// ahead; MFMA chains interleaved kt-outer.
// ---------------------------------------------------------------------------
__device__ void h2_role(
    const u16* __restrict__ U2, const u16* __restrict__ gw,
    const u16* __restrict__ o2w,
    const float* __restrict__ W2c, const float* __restrict__ G1c,
    const float* __restrict__ O1c,
    float* __restrict__ out, float* __restrict__ h2state,
    float* __restrict__ ustate, int cm1, u16 (*buf)[H_ + 8])
{
    const int g = blockIdx.x - 16;
    const int tid = threadIdx.x;
    const int w = tid >> 6, lane = tid & 63;
    const int col = lane & 15, quad = lane >> 4;
    const int t0 = cm1 * Tc_;

    bf8 u2f[4][8], g2f[4][8], o2f[8];
#pragma unroll
    for (int i = 0; i < 4; ++i) {
        const int n = (w * 4 + i) * 16 + col;
#pragma unroll
        for (int kt = 0; kt < 8; ++kt) {
            u2f[i][kt] = *(const bf8*)(U2 + (size_t)n * H_ + kt * 32 + quad * 8);
            g2f[i][kt] = *(const bf8*)(gw + (size_t)n * (2 * H_) + H_ + kt * 32 + quad * 8);
        }
    }
#pragma unroll
    for (int kt = 0; kt < 8; ++kt)
        o2f[kt] = *(const bf8*)(o2w + (size_t)(w * 16 + col) * H_ + kt * 32 + quad * 8);

    f32x4 h2p[4], up[4];
    if (cm1 == 0) {
#pragma unroll
        for (int i = 0; i < 4; ++i) {
            h2p[i][0]=0.f; h2p[i][1]=0.f; h2p[i][2]=0.f; h2p[i][3]=0.f;
            up[i][0]=1.f;  up[i][1]=1.f;  up[i][2]=1.f;  up[i][3]=1.f;
        }
    } else {
#pragma unroll
        for (int i = 0; i < 4; ++i) {
            size_t idx = (((size_t)g * 16 + (w * 4 + i)) * 64 + lane) * 4;
            h2p[i] = *(const f32x4*)(h2state + idx);
            up[i]  = *(const f32x4*)(ustate + idx);
        }
    }

#pragma unroll
    for (int i = 0; i < 4; ++i) {
        const int n = (w * 4 + i) * 16 + col;
#pragma unroll
        for (int r = 0; r < 4; ++r) buf[quad * 4 + r][n] = f2b(h2p[i][r]);
    }
    __syncthreads();
    bf8 h2af[8];
#pragma unroll
    for (int kt = 0; kt < 8; ++kt)
        h2af[kt] = *(const bf8*)&buf[col][kt * 32 + quad * 8];
    __syncthreads();

    // prefetch step 0
    f32x4 w2cr[4], g1cr[4], o1cr;
#pragma unroll
    for (int i = 0; i < 4; ++i) {
        size_t idx = ((((size_t)g * Tc_ + 0) * 16 + (w * 4 + i)) * 64 + lane) * 4;
        w2cr[i] = *(const f32x4*)(W2c + idx);
        g1cr[i] = *(const f32x4*)(G1c + idx);
    }
    o1cr = *(const f32x4*)(O1c + ((((size_t)g * Tc_ + 0) * 4 + w) * 64 + lane) * 4);

    for (int tt = 0; tt < Tc_; ++tt) {
        const int ttn = (tt + 1 < Tc_) ? tt + 1 : tt;
        f32x4 w2cn[4], g1cn[4], o1cn;
#pragma unroll
        for (int i = 0; i < 4; ++i) {
            size_t idx = ((((size_t)g * Tc_ + ttn) * 16 + (w * 4 + i)) * 64 + lane) * 4;
            w2cn[i] = *(const f32x4*)(W2c + idx);
            g1cn[i] = *(const f32x4*)(G1c + idx);
        }
        o1cn = *(const f32x4*)(O1c + ((((size_t)g * Tc_ + ttn) * 4 + w) * 64 + lane) * 4);

        // h2 preact: prefetched (W2@h1+biases) + U2 @ h2_prev, 4 chains kt-outer
        f32x4 acc1[4];
#pragma unroll
        for (int i = 0; i < 4; ++i) acc1[i] = w2cr[i];
#pragma unroll
        for (int kt = 0; kt < 8; ++kt)
#pragma unroll
            for (int i = 0; i < 4; ++i)
                acc1[i] = MFMA(h2af[kt], u2f[i][kt], acc1[i]);

#pragma unroll
        for (int i = 0; i < 4; ++i)
#pragma unroll
            for (int r = 0; r < 4; ++r) {
                float h2n = fast_tanh(acc1[i][r]);
                h2p[i][r] = up[i][r] * h2n + (1.f - up[i][r]) * h2p[i][r];
            }
#pragma unroll
        for (int i = 0; i < 4; ++i) {
            const int n = (w * 4 + i) * 16 + col;
#pragma unroll
            for (int r = 0; r < 4; ++r) buf[quad * 4 + r][n] = f2b(h2p[i][r]);
        }
        __syncthreads();
#pragma unroll
        for (int kt = 0; kt < 8; ++kt)
            h2af[kt] = *(const bf8*)&buf[col][kt * 32 + quad * 8];
        __syncthreads();

        // out + gate: 5 independent chains interleaved kt-outer
        f32x4 accg[4], acco = o1cr;
#pragma unroll
        for (int i = 0; i < 4; ++i) accg[i] = g1cr[i];
#pragma unroll
        for (int kt = 0; kt < 8; ++kt) {
            acco = MFMA(h2af[kt], o2f[kt], acco);
#pragma unroll
            for (int i = 0; i < 4; ++i)
                accg[i] = MFMA(h2af[kt], g2f[i][kt], accg[i]);
        }
        const int t = t0 + tt;
#pragma unroll
        for (int r = 0; r < 4; ++r)
            out[((size_t)(g * 16 + quad * 4 + r) * T_ + t) * D_ + w * 16 + col] =
                acco[r];
#pragma unroll
        for (int i = 0; i < 4; ++i)
#pragma unroll
            for (int r = 0; r < 4; ++r) up[i][r] = fast_sigmoid(accg[i][r]);

#pragma unroll
        for (int i = 0; i < 4; ++i) { w2cr[i] = w2cn[i]; g1cr[i] = g1cn[i]; }
        o1cr = o1cn;
    }
#pragma unroll
    for (int i = 0; i < 4; ++i) {
        size_t idx = (((size_t)g * 16 + (w * 4 + i)) * 64 + lane) * 4;
        *(f32x4*)(h2state + idx) = h2p[i];
        *(f32x4*)(ustate + idx)  = up[i];
    }
}

// ---------------------------------------------------------------------------
// k_pipe: blocks 0-15 run h1 for chunk c; blocks 16-31 run h2 for chunk c-1.
// The two roles are dataflow-independent (h1 chain doesn't see h2).
// ---------------------------------------------------------------------------
__global__ __launch_bounds__(256, 1) void k_pipe(
    const float* __restrict__ x, const u16* __restrict__ W1,
    const u16* __restrict__ U1, const float* __restrict__ W1b,
    const float* __restrict__ U1b, u16* __restrict__ H1,
    u16* __restrict__ h1state,
    const u16* __restrict__ U2, const u16* __restrict__ gw,
    const u16* __restrict__ o2w,
    const float* __restrict__ W2c, const float* __restrict__ G1c,
    const float* __restrict__ O1c,
    float* __restrict__ out, float* __restrict__ h2state,
    float* __restrict__ ustate, int c)
{
    __shared__ __align__(16) u16 buf[16][H_ + 8];
    if (blockIdx.x < 16) {
        if (c < NC_)
            h1_role(x, W1, U1, W1b, U1b, H1, h1state, c, buf);
    } else {
        if (c >= 1)
            h2_role(U2, gw, o2w, W2c, G1c, O1c, out, h2state, ustate, c - 1, buf);
    }
}

// ---------------------------------------------------------------------------
// K_G: chunk GEMM (unchanged math, Tc_=64, parity buffers).
// ---------------------------------------------------------------------------
__global__ __launch_bounds__(256, 1) void k_gemm(
    const u16* __restrict__ H1,
    const u16* __restrict__ W2, const u16* __restrict__ gw,
    const u16* __restrict__ o1w,
    const float* __restrict__ W2b, const float* __restrict__ U2b,
    const float* __restrict__ gb, const float* __restrict__ o1b,
    const float* __restrict__ o2b,
    float* __restrict__ W2c, float* __restrict__ G1c, float* __restrict__ O1c)
{
    const int mt = blockIdx.x, ny = blockIdx.y;
    const int tid = threadIdx.x;
    const int w = tid >> 6, lane = tid & 63;
    const int col = lane & 15, quad = lane >> 4;
    const int mrow = mt * 64 + w * 16;

    f32x4 acc[4];
#pragma unroll
    for (int i = 0; i < 4; ++i) { acc[i][0]=0.f; acc[i][1]=0.f; acc[i][2]=0.f; acc[i][3]=0.f; }

#pragma unroll
    for (int kt = 0; kt < 8; ++kt) {
        const int k = kt * 32 + quad * 8;
        bf8 af = *(const bf8*)(H1 + (size_t)(mrow + col) * H_ + k);
#pragma unroll
        for (int i = 0; i < 4; ++i) {
            const int n = ny * 64 + i * 16 + col;
            const u16* bp;
            if (n < 256)      bp = W2  + (size_t)n * H_ + k;
            else if (n < 512) bp = gw  + (size_t)(n - 256) * (2 * H_) + k;
            else              bp = o1w + (size_t)(n - 512) * H_ + k;
            bf8 bfv = *(const bf8*)bp;
            acc[i] = MFMA(af, bfv, acc[i]);
        }
    }

    const int tt = mrow >> 8;
    const int g  = (mrow & 255) >> 4;
#pragma unroll
    for (int i = 0; i < 4; ++i) {
        const int n = ny * 64 + i * 16 + col;
        float bias;
        if (n < 256)      bias = W2b[n] + U2b[n];
        else if (n < 512) bias = gb[n - 256];
        else              bias = o1b[n - 512] + o2b[n - 512];
        f32x4 v;
#pragma unroll
        for (int r = 0; r < 4; ++r) v[r] = acc[i][r] + bias;
        const int nt = ny * 4 + i;
        if (nt < 16) {
            size_t idx = ((((size_t)g * Tc_ + tt) * 16 + nt) * 64 + lane) * 4;
            *(f32x4*)(W2c + idx) = v;
        } else if (nt < 32) {
            size_t idx = ((((size_t)g * Tc_ + tt) * 16 + (nt - 16)) * 64 + lane) * 4;
            *(f32x4*)(G1c + idx) = v;
        } else {
            size_t idx = ((((size_t)g * Tc_ + tt) * 4 + (nt - 32)) * 64 + lane) * 4;
            *(f32x4*)(O1c + idx) = v;
        }
    }
}

// ---------------------------------------------------------------------------
extern "C" void kernel_launch(void* const* d_in, const int* in_sizes, int n_in,
                              void* d_out, int out_size, void* d_ws, size_t ws_size,
                              hipStream_t stream)
{
    const float* x   = (const float*)d_in[0];
    const float* W1w = (const float*)d_in[1];
    const float* W1b = (const float*)d_in[2];
    const float* U1w = (const float*)d_in[3];
    const float* U1b = (const float*)d_in[4];
    const float* W2w = (const float*)d_in[5];
    const float* W2b = (const float*)d_in[6];
    const float* U2w = (const float*)d_in[7];
    const float* U2b = (const float*)d_in[8];
    const float* o1w = (const float*)d_in[9];
    const float* o1b = (const float*)d_in[10];
    const float* o2w = (const float*)d_in[11];
    const float* o2b = (const float*)d_in[12];
    const float* gw  = (const float*)d_in[13];
    const float* gb  = (const float*)d_in[14];
    float* out = (float*)d_out;
    (void)in_sizes; (void)n_in; (void)out_size; (void)ws_size;

    char* p = (char*)d_ws;
    u16* W1bf = (u16*)p; p += 16384 * 2;
    u16* U1bf = (u16*)p; p += 65536 * 2;
    u16* W2bf = (u16*)p; p += 65536 * 2;
    u16* U2bf = (u16*)p; p += 65536 * 2;
    u16* o1bf = (u16*)p; p += 16384 * 2;
    u16* o2bf = (u16*)p; p += 16384 * 2;
    u16* gbf  = (u16*)p; p += 131072 * 2;
    u16* H1[2]; float* W2c[2]; float* G1c[2]; float* O1c[2];
    for (int pa = 0; pa < 2; ++pa) {
        H1[pa]  = (u16*)p;   p += (size_t)Tc_ * 131072;   // Tc*256*256 bf16
        W2c[pa] = (float*)p; p += (size_t)Tc_ * 262144;   // Tc*256*256 f32
        G1c[pa] = (float*)p; p += (size_t)Tc_ * 262144;
        O1c[pa] = (float*)p; p += (size_t)Tc_ * 65536;    // Tc*256*64 f32
    }
    u16* h1s   = (u16*)p;  p += 131072;
    float* h2s = (float*)p; p += 262144;
    float* us  = (float*)p;

    k_conv<<<dim3(128, 7), 256, 0, stream>>>(W1w, U1w, W2w, U2w, o1w, o2w, gw,
                                             W1bf, U1bf, W2bf, U2bf, o1bf, o2bf, gbf);

    for (int c = 0; c <= NC_; ++c) {
        const int pa = c & 1, pb = (c - 1) & 1;
        k_pipe<<<32, 256, 0, stream>>>(x, W1bf, U1bf, W1b, U1b, H1[pa], h1s,
                                       U2bf, gbf, o2bf, W2c[pb], G1c[pb], O1c[pb],
                                       out, h2s, us, c);
        if (c < NC_)
            k_gemm<<<dim3(Tc_ * 4, 9), 256, 0, stream>>>(
                H1[pa], W2bf, gbf, o1bf, W2b, U2b, gb, o1b, o2b,
                W2c[pa], G1c[pa], O1c[pa]);
    }
}

// Round 5
// 1323.308 us; speedup vs baseline: 2.8596x; 1.3788x over previous
//
#include <hip/hip_runtime.h>

typedef unsigned short u16;
using bf8   = __attribute__((ext_vector_type(8))) short;  // 8 bf16 (4 VGPRs)
using bf4   = __attribute__((ext_vector_type(4))) short;  // 4 bf16
using f32x4 = __attribute__((ext_vector_type(4))) float;

#define B_ 256
#define T_ 512
#define D_ 64
#define H_ 256
#define Tc_ 64
#define NC_ (T_ / Tc_)
#define GEMMB_ 192   // gemm role blocks; 32+192=224 <= 256 CUs

#define MFMA(a, b, c) __builtin_amdgcn_mfma_f32_16x16x32_bf16(a, b, c, 0, 0, 0)

static __device__ inline u16 f2b(float f) {
    unsigned int u = __float_as_uint(f);
    unsigned int r = (u + 0x7fffu + ((u >> 16) & 1u)) >> 16;
    return (u16)r;
}
static __device__ inline float fast_tanh(float x) {
    float e = __expf(2.f * x);
    return 1.f - 2.f / (e + 1.f);
}
static __device__ inline float fast_sigmoid(float x) {
    return 1.f / (1.f + __expf(-x));
}

// ---------------------------------------------------------------------------
// k_conv: f32 -> bf16 weight conversion pre-pass.
// ---------------------------------------------------------------------------
__global__ __launch_bounds__(256) void k_conv(
    const float* __restrict__ W1w, const float* __restrict__ U1w,
    const float* __restrict__ W2w, const float* __restrict__ U2w,
    const float* __restrict__ o1w, const float* __restrict__ o2w,
    const float* __restrict__ gw,
    u16* W1bf, u16* U1bf, u16* W2bf, u16* U2bf,
    u16* o1bf, u16* o2bf, u16* gbf)
{
    const int a = blockIdx.y;
    const float* src; u16* dst; int n;
    switch (a) {
        case 0: src = W1w; dst = W1bf; n = 16384;  break;
        case 1: src = U1w; dst = U1bf; n = 65536;  break;
        case 2: src = W2w; dst = W2bf; n = 65536;  break;
        case 3: src = U2w; dst = U2bf; n = 65536;  break;
        case 4: src = o1w; dst = o1bf; n = 16384;  break;
        case 5: src = o2w; dst = o2bf; n = 16384;  break;
        default: src = gw; dst = gbf;  n = 131072; break;
    }
    const int i = (blockIdx.x * 256 + threadIdx.x) * 4;
    if (i < n) {
        f32x4 v = *(const f32x4*)(src + i);
        bf4 o;
        o[0] = (short)f2b(v[0]); o[1] = (short)f2b(v[1]);
        o[2] = (short)f2b(v[2]); o[3] = (short)f2b(v[3]);
        *(bf4*)(dst + i) = o;
    }
}

// ---------------------------------------------------------------------------
// h1 role: blocks 0-15. Chunk c. 8 waves, 2 n-chains each.
// ---------------------------------------------------------------------------
__device__ void h1_role(
    const float* __restrict__ x, const u16* __restrict__ W1,
    const u16* __restrict__ U1, const float* __restrict__ W1b,
    const float* __restrict__ U1b, u16* __restrict__ H1,
    u16* __restrict__ h1state, int c, u16 (*buf)[H_ + 8])
{
    const int g = blockIdx.x;
    const int tid = threadIdx.x;
    const int w = tid >> 6, lane = tid & 63;
    const int col = lane & 15, quad = lane >> 4;
    const int t0 = c * Tc_;

    bf8 u1f[2][8], w1f[2][2];
    float bias[2];
#pragma unroll
    for (int i = 0; i < 2; ++i) {
        const int n = (w * 2 + i) * 16 + col;
#pragma unroll
        for (int kt = 0; kt < 8; ++kt)
            u1f[i][kt] = *(const bf8*)(U1 + (size_t)n * H_ + kt * 32 + quad * 8);
#pragma unroll
        for (int kt = 0; kt < 2; ++kt)
            w1f[i][kt] = *(const bf8*)(W1 + (size_t)n * D_ + kt * 32 + quad * 8);
        bias[i] = W1b[n] + U1b[n];
    }

    if (c == 0) {
        for (int idx = tid; idx < 16 * (H_ + 8); idx += 512)
            ((u16*)buf)[idx] = 0;
    } else {
        const int m = tid >> 5, hb = (tid & 31) * 8;
#pragma unroll
        for (int j = 0; j < 8; ++j)
            buf[m][hb + j] = h1state[(size_t)(g * 16 + m) * H_ + hb + j];
    }
    __syncthreads();

    const float* xrow = x + (size_t)(g * 16 + col) * T_ * D_ + quad * 8;
    f32x4 xa[4];
    {
        const float* xp = xrow + (size_t)t0 * D_;
        xa[0] = *(const f32x4*)xp;        xa[1] = *(const f32x4*)(xp + 4);
        xa[2] = *(const f32x4*)(xp + 32); xa[3] = *(const f32x4*)(xp + 36);
    }

    for (int tt = 0; tt < Tc_; ++tt) {
        const int tn = t0 + (tt + 1 < Tc_ ? tt + 1 : tt);
        f32x4 xan[4];
        {
            const float* xp = xrow + (size_t)tn * D_;
            xan[0] = *(const f32x4*)xp;        xan[1] = *(const f32x4*)(xp + 4);
            xan[2] = *(const f32x4*)(xp + 32); xan[3] = *(const f32x4*)(xp + 36);
        }
        bf8 haf[8];
#pragma unroll
        for (int kt = 0; kt < 8; ++kt)
            haf[kt] = *(const bf8*)&buf[col][kt * 32 + quad * 8];
        __syncthreads();  // reads done before overwrite

        bf8 xaf[2];
#pragma unroll
        for (int kt = 0; kt < 2; ++kt) {
            bf8 v;
#pragma unroll
            for (int j = 0; j < 4; ++j) {
                v[j]     = (short)f2b(xa[kt * 2][j]);
                v[j + 4] = (short)f2b(xa[kt * 2 + 1][j]);
            }
            xaf[kt] = v;
        }

        f32x4 acc[2];
#pragma unroll
        for (int i = 0; i < 2; ++i) {
            acc[i][0] = bias[i]; acc[i][1] = bias[i];
            acc[i][2] = bias[i]; acc[i][3] = bias[i];
        }
#pragma unroll
        for (int kt = 0; kt < 8; ++kt)
#pragma unroll
            for (int i = 0; i < 2; ++i)
                acc[i] = MFMA(haf[kt], u1f[i][kt], acc[i]);
#pragma unroll
        for (int kt = 0; kt < 2; ++kt)
#pragma unroll
            for (int i = 0; i < 2; ++i)
                acc[i] = MFMA(xaf[kt], w1f[i][kt], acc[i]);

#pragma unroll
        for (int i = 0; i < 2; ++i) {
            const int n = (w * 2 + i) * 16 + col;
#pragma unroll
            for (int r = 0; r < 4; ++r)
                buf[quad * 4 + r][n] = f2b(fast_tanh(acc[i][r]));
        }
        __syncthreads();
        {
            const int m = tid >> 5, hb = (tid & 31) * 8;
            bf8 v0 = *(const bf8*)&buf[m][hb];
            u16* dst = H1 + ((size_t)tt * 256 + g * 16 + m) * H_ + hb;
            *(bf8*)dst = v0;
        }
        xa[0] = xan[0]; xa[1] = xan[1]; xa[2] = xan[2]; xa[3] = xan[3];
    }
    __syncthreads();
    {
        const int m = tid >> 5, hb = (tid & 31) * 8;
#pragma unroll
        for (int j = 0; j < 8; ++j)
            h1state[(size_t)(g * 16 + m) * H_ + hb + j] = buf[m][hb + j];
    }
}

// ---------------------------------------------------------------------------
// h2 role: blocks 16-31. Chunk ch. 8 waves, 2 n-chains each; out on waves 0-3.
// W2c prefetched one step ahead; G1c/O1c loaded at top of step, consumed
// after the U2/tanh/LDS section (~600 cy of cover).
// ---------------------------------------------------------------------------
__device__ void h2_role(
    const u16* __restrict__ U2, const u16* __restrict__ gw,
    const u16* __restrict__ o2w,
    const float* __restrict__ W2c, const float* __restrict__ G1c,
    const float* __restrict__ O1c,
    float* __restrict__ out, float* __restrict__ h2state,
    float* __restrict__ ustate, int ch, u16 (*buf)[H_ + 8])
{
    const int g = blockIdx.x - 16;
    const int tid = threadIdx.x;
    const int w = tid >> 6, lane = tid & 63;
    const int col = lane & 15, quad = lane >> 4;
    const int t0 = ch * Tc_;

    bf8 u2f[2][8], g2f[2][8], o2f[8];
#pragma unroll
    for (int i = 0; i < 2; ++i) {
        const int n = (w * 2 + i) * 16 + col;
#pragma unroll
        for (int kt = 0; kt < 8; ++kt) {
            u2f[i][kt] = *(const bf8*)(U2 + (size_t)n * H_ + kt * 32 + quad * 8);
            g2f[i][kt] = *(const bf8*)(gw + (size_t)n * (2 * H_) + H_ + kt * 32 + quad * 8);
        }
    }
    if (w < 4) {
#pragma unroll
        for (int kt = 0; kt < 8; ++kt)
            o2f[kt] = *(const bf8*)(o2w + (size_t)(w * 16 + col) * H_ + kt * 32 + quad * 8);
    }

    f32x4 h2p[2], up[2];
    if (ch == 0) {
#pragma unroll
        for (int i = 0; i < 2; ++i) {
            h2p[i][0]=0.f; h2p[i][1]=0.f; h2p[i][2]=0.f; h2p[i][3]=0.f;
            up[i][0]=1.f;  up[i][1]=1.f;  up[i][2]=1.f;  up[i][3]=1.f;
        }
    } else {
#pragma unroll
        for (int i = 0; i < 2; ++i) {
            size_t idx = (((size_t)g * 16 + (w * 2 + i)) * 64 + lane) * 4;
            h2p[i] = *(const f32x4*)(h2state + idx);
            up[i]  = *(const f32x4*)(ustate + idx);
        }
    }

#pragma unroll
    for (int i = 0; i < 2; ++i) {
        const int n = (w * 2 + i) * 16 + col;
#pragma unroll
        for (int r = 0; r < 4; ++r) buf[quad * 4 + r][n] = f2b(h2p[i][r]);
    }
    __syncthreads();
    bf8 h2af[8];
#pragma unroll
    for (int kt = 0; kt < 8; ++kt)
        h2af[kt] = *(const bf8*)&buf[col][kt * 32 + quad * 8];
    __syncthreads();

    // cross-step prefetch: W2c for step 0
    f32x4 w2cr[2];
#pragma unroll
    for (int i = 0; i < 2; ++i)
        w2cr[i] = *(const f32x4*)(W2c +
            ((((size_t)g * Tc_ + 0) * 16 + (w * 2 + i)) * 64 + lane) * 4);

    for (int tt = 0; tt < Tc_; ++tt) {
        const int ttn = (tt + 1 < Tc_) ? tt + 1 : tt;
        // next-step W2c + current-step G1c/O1c (consumed after barrier section)
        f32x4 w2cn[2], g1cc[2], o1cc;
#pragma unroll
        for (int i = 0; i < 2; ++i) {
            w2cn[i] = *(const f32x4*)(W2c +
                ((((size_t)g * Tc_ + ttn) * 16 + (w * 2 + i)) * 64 + lane) * 4);
            g1cc[i] = *(const f32x4*)(G1c +
                ((((size_t)g * Tc_ + tt) * 16 + (w * 2 + i)) * 64 + lane) * 4);
        }
        if (w < 4)
            o1cc = *(const f32x4*)(O1c +
                ((((size_t)g * Tc_ + tt) * 4 + w) * 64 + lane) * 4);

        // h2 preact: prefetched (W2@h1+biases) + U2 @ h2_prev
        f32x4 acc1[2];
#pragma unroll
        for (int i = 0; i < 2; ++i) acc1[i] = w2cr[i];
#pragma unroll
        for (int kt = 0; kt < 8; ++kt)
#pragma unroll
            for (int i = 0; i < 2; ++i)
                acc1[i] = MFMA(h2af[kt], u2f[i][kt], acc1[i]);

#pragma unroll
        for (int i = 0; i < 2; ++i)
#pragma unroll
            for (int r = 0; r < 4; ++r) {
                float h2n = fast_tanh(acc1[i][r]);
                h2p[i][r] = up[i][r] * h2n + (1.f - up[i][r]) * h2p[i][r];
            }
#pragma unroll
        for (int i = 0; i < 2; ++i) {
            const int n = (w * 2 + i) * 16 + col;
#pragma unroll
            for (int r = 0; r < 4; ++r) buf[quad * 4 + r][n] = f2b(h2p[i][r]);
        }
        __syncthreads();
#pragma unroll
        for (int kt = 0; kt < 8; ++kt)
            h2af[kt] = *(const bf8*)&buf[col][kt * 32 + quad * 8];
        __syncthreads();

        // gate (+ out on waves 0-3): independent chains interleaved kt-outer
        f32x4 accg[2], acco;
#pragma unroll
        for (int i = 0; i < 2; ++i) accg[i] = g1cc[i];
        if (w < 4) {
            acco = o1cc;
#pragma unroll
            for (int kt = 0; kt < 8; ++kt) {
                acco = MFMA(h2af[kt], o2f[kt], acco);
#pragma unroll
                for (int i = 0; i < 2; ++i)
                    accg[i] = MFMA(h2af[kt], g2f[i][kt], accg[i]);
            }
            const int t = t0 + tt;
#pragma unroll
            for (int r = 0; r < 4; ++r)
                out[((size_t)(g * 16 + quad * 4 + r) * T_ + t) * D_ + w * 16 + col] =
                    acco[r];
        } else {
#pragma unroll
            for (int kt = 0; kt < 8; ++kt)
#pragma unroll
                for (int i = 0; i < 2; ++i)
                    accg[i] = MFMA(h2af[kt], g2f[i][kt], accg[i]);
        }
#pragma unroll
        for (int i = 0; i < 2; ++i)
#pragma unroll
            for (int r = 0; r < 4; ++r) up[i][r] = fast_sigmoid(accg[i][r]);

#pragma unroll
        for (int i = 0; i < 2; ++i) w2cr[i] = w2cn[i];
    }
#pragma unroll
    for (int i = 0; i < 2; ++i) {
        size_t idx = (((size_t)g * 16 + (w * 2 + i)) * 64 + lane) * 4;
        *(f32x4*)(h2state + idx) = h2p[i];
        *(f32x4*)(ustate + idx)  = up[i];
    }
}

// ---------------------------------------------------------------------------
// k_pipe, lag-2 software pipeline across dispatches:
//   blocks 0-15 : h1 of chunk c          (c < NC_)
//   blocks 16-31: h2 of chunk c-2        (c >= 2)
//   blocks 32+  : gemm of chunk c-1      (1 <= c <= NC_)
// All producer->consumer edges cross a dispatch boundary (no intra-grid sync).
// ---------------------------------------------------------------------------
__global__ __launch_bounds__(512, 2) void k_pipe(
    const float* __restrict__ x, const u16* __restrict__ W1,
    const u16* __restrict__ U1, const float* __restrict__ W1b,
    const float* __restrict__ U1b, u16* __restrict__ H1w,
    u16* __restrict__ h1state,
    const u16* __restrict__ U2, const u16* __restrict__ gwgt,
    const u16* __restrict__ o2w,
    const float* __restrict__ W2cr, const float* __restrict__ G1cr,
    const float* __restrict__ O1cr,
    float* __restrict__ out, float* __restrict__ h2state,
    float* __restrict__ ustate,
    const u16* __restrict__ H1r, const u16* __restrict__ W2,
    const u16* __restrict__ o1w,
    const float* __restrict__ W2b, const float* __restrict__ U2b,
    const float* __restrict__ gbias, const float* __restrict__ o1b,
    const float* __restrict__ o2b,
    float* __restrict__ W2cw, float* __restrict__ G1cw, float* __restrict__ O1cw,
    int c)
{
    __shared__ __align__(16) u16 buf[16][H_ + 8];
    if (blockIdx.x < 16) {
        if (c < NC_)
            h1_role(x, W1, U1, W1b, U1b, H1w, h1state, c, buf);
    } else if (blockIdx.x < 32) {
        if (c >= 2)
            h2_role(U2, gwgt, o2w, W2cr, G1cr, O1cr, out, h2state, ustate, c - 2, buf);
    } else {
        if (c >= 1 && c <= NC_) {
            const int gbk = blockIdx.x - 32;
            const int tid = threadIdx.x;
            const int w = tid >> 6, lane = tid & 63;
            const int col = lane & 15, quad = lane >> 4;
            const int Wv = gbk * 8 + w;
            const int NT = (Tc_ * 256 / 16) * 9;   // 9216 wave-tasks

            for (int task = Wv; task < NT; task += GEMMB_ * 8) {
                const int mt = task & 1023, ny = task >> 10;
                const int mrow = mt * 16;

                f32x4 acc[4];
#pragma unroll
                for (int i = 0; i < 4; ++i) { acc[i][0]=0.f; acc[i][1]=0.f; acc[i][2]=0.f; acc[i][3]=0.f; }

#pragma unroll
                for (int kt = 0; kt < 8; ++kt) {
                    const int k = kt * 32 + quad * 8;
                    bf8 af = *(const bf8*)(H1r + (size_t)(mrow + col) * H_ + k);
#pragma unroll
                    for (int i = 0; i < 4; ++i) {
                        const int n = ny * 64 + i * 16 + col;
                        const u16* bp;
                        if (n < 256)      bp = W2   + (size_t)n * H_ + k;
                        else if (n < 512) bp = gwgt + (size_t)(n - 256) * (2 * H_) + k;
                        else              bp = o1w  + (size_t)(n - 512) * H_ + k;
                        bf8 bfv = *(const bf8*)bp;
                        acc[i] = MFMA(af, bfv, acc[i]);
                    }
                }

                const int tt = mrow >> 8;
                const int g  = (mrow & 255) >> 4;
#pragma unroll
                for (int i = 0; i < 4; ++i) {
                    const int n = ny * 64 + i * 16 + col;
                    float bias;
                    if (n < 256)      bias = W2b[n] + U2b[n];
                    else if (n < 512) bias = gbias[n - 256];
                    else              bias = o1b[n - 512] + o2b[n - 512];
                    f32x4 v;
#pragma unroll
                    for (int r = 0; r < 4; ++r) v[r] = acc[i][r] + bias;
                    const int nt = ny * 4 + i;
                    if (nt < 16) {
                        size_t idx = ((((size_t)g * Tc_ + tt) * 16 + nt) * 64 + lane) * 4;
                        *(f32x4*)(W2cw + idx) = v;
                    } else if (nt < 32) {
                        size_t idx = ((((size_t)g * Tc_ + tt) * 16 + (nt - 16)) * 64 + lane) * 4;
                        *(f32x4*)(G1cw + idx) = v;
                    } else {
                        size_t idx = ((((size_t)g * Tc_ + tt) * 4 + (nt - 32)) * 64 + lane) * 4;
                        *(f32x4*)(O1cw + idx) = v;
                    }
                }
            }
        }
    }
}

// ---------------------------------------------------------------------------
extern "C" void kernel_launch(void* const* d_in, const int* in_sizes, int n_in,
                              void* d_out, int out_size, void* d_ws, size_t ws_size,
                              hipStream_t stream)
{
    const float* x   = (const float*)d_in[0];
    const float* W1w = (const float*)d_in[1];
    const float* W1b = (const float*)d_in[2];
    const float* U1w = (const float*)d_in[3];
    const float* U1b = (const float*)d_in[4];
    const float* W2w = (const float*)d_in[5];
    const float* W2b = (const float*)d_in[6];
    const float* U2w = (const float*)d_in[7];
    const float* U2b = (const float*)d_in[8];
    const float* o1w = (const float*)d_in[9];
    const float* o1b = (const float*)d_in[10];
    const float* o2w = (const float*)d_in[11];
    const float* o2b = (const float*)d_in[12];
    const float* gw  = (const float*)d_in[13];
    const float* gb  = (const float*)d_in[14];
    float* out = (float*)d_out;
    (void)in_sizes; (void)n_in; (void)out_size; (void)ws_size;

    char* p = (char*)d_ws;
    u16* W1bf = (u16*)p; p += 16384 * 2;
    u16* U1bf = (u16*)p; p += 65536 * 2;
    u16* W2bf = (u16*)p; p += 65536 * 2;
    u16* U2bf = (u16*)p; p += 65536 * 2;
    u16* o1bf = (u16*)p; p += 16384 * 2;
    u16* o2bf = (u16*)p; p += 16384 * 2;
    u16* gbf  = (u16*)p; p += 131072 * 2;
    u16* H1[2]; float* W2c[2]; float* G1c[2]; float* O1c[2];
    for (int pa = 0; pa < 2; ++pa) {
        H1[pa]  = (u16*)p;   p += (size_t)Tc_ * 131072;   // Tc*256*256 bf16
        W2c[pa] = (float*)p; p += (size_t)Tc_ * 262144;   // Tc*256*256 f32
        G1c[pa] = (float*)p; p += (size_t)Tc_ * 262144;
        O1c[pa] = (float*)p; p += (size_t)Tc_ * 65536;    // Tc*256*64 f32
    }
    u16* h1s   = (u16*)p;  p += 131072;
    float* h2s = (float*)p; p += 262144;
    float* us  = (float*)p;

    k_conv<<<dim3(128, 7), 256, 0, stream>>>(W1w, U1w, W2w, U2w, o1w, o2w, gw,
                                             W1bf, U1bf, W2bf, U2bf, o1bf, o2bf, gbf);

    // lag-2 pipeline: dispatch c = { h1(c), gemm(c-1), h2(c-2) }
    for (int c = 0; c <= NC_ + 1; ++c) {
        const int pw = c & 1;         // h1 writes chunk c
        const int pg = (c + 1) & 1;   // gemm: chunk c-1  (reads H1[pg], writes C[pg])
        const int ph = c & 1;         // h2: chunk c-2    (reads C[ph])
        k_pipe<<<32 + GEMMB_, 512, 0, stream>>>(
            x, W1bf, U1bf, W1b, U1b, H1[pw], h1s,
            U2bf, gbf, o2bf, W2c[ph], G1c[ph], O1c[ph],
            out, h2s, us,
            H1[pg], W2bf, o1bf, W2b, U2b, gb, o1b, o2b,
            W2c[pg], G1c[pg], O1c[pg], c);
    }
}